// Round 9
// baseline (209.688 us; speedup 1.0000x reference)
//
#include <hip/hip_runtime.h>

namespace {

typedef _Float16 f16;
typedef __attribute__((ext_vector_type(4))) _Float16 f16x4;
typedef __attribute__((ext_vector_type(8))) _Float16 f16x8;
typedef __attribute__((ext_vector_type(4))) float f32x4;

constexpr int kDim   = 1024;
constexpr int kHeads = 16;
constexpr int kHd    = 64;
constexpr int kB     = 2;
constexpr int kL     = 1024;
constexpr int kS     = 2048;

__device__ inline f16x8 cvt8(float4 a, float4 b) {
  return (f16x8){(f16)a.x, (f16)a.y, (f16)a.z, (f16)a.w,
                 (f16)b.x, (f16)b.y, (f16)b.z, (f16)b.w};
}

// ---------------- prep: weight transposes only (W[k][n] f32 -> Wt[n][k] f16)
struct PrepWArgs {
  const float* w[4];
  f16* wt[4];
};

__global__ __launch_bounds__(256) void prep_w(PrepWArgs a) {
  __shared__ float T[32][33];
  const int z = blockIdx.y;
  const float* __restrict__ W = a.w[z];
  f16* __restrict__ Wt = a.wt[z];
  const int n0 = (blockIdx.x & 31) * 32;
  const int k0 = (blockIdx.x >> 5) * 32;
  const int r = threadIdx.x >> 3;
  const int c = (threadIdx.x & 7) * 4;
  float4 v = *(const float4*)(W + (size_t)(k0 + r) * kDim + n0 + c);
  T[c + 0][r] = v.x; T[c + 1][r] = v.y; T[c + 2][r] = v.z; T[c + 3][r] = v.w;
  __syncthreads();
  f16x4 h = {(f16)T[r][c], (f16)T[r][c + 1], (f16)T[r][c + 2], (f16)T[r][c + 3]};
  *(f16x4*)(Wt + (size_t)(n0 + r) * kDim + k0 + c) = h;
}

// ------------- fused projection GEMMs, fp32-direct staging ----------------
// z<2:  C = act(fp32)[M][K] @ Wt(f16)[N][K]^T    (act->As, Wt->Bs)
// z==2: C = WvT(f16)[1024][K] @ value(fp32)[4096][K]^T  (WvT->As, value->Bs)
// The fp32 operand is cast at the LDS-store site (after the MFMAs) so the
// global-load wait stays sunk below the compute.
struct ProjArgs {
  const float* Xf[3];  // fp32 operand: query, key, value
  const f16* Yh[3];    // f16 operand: wqt, wkt, wvt
  f16* C[3];
};

__global__ __launch_bounds__(256) void gemm_proj(ProjArgs p) {
  constexpr int K = kDim;
  constexpr int NI = K / 32;
  int bx = blockIdx.x;
  int z, m0, n0, Nz;
  if (bx < 128)      { z = 0; m0 = (bx >> 3) * 128; n0 = (bx & 7) * 128; Nz = kDim; }
  else if (bx < 384) { bx -= 128; z = 1; m0 = (bx >> 3) * 128; n0 = (bx & 7) * 128; Nz = kDim; }
  else               { bx -= 384; z = 2; m0 = (bx >> 5) * 128; n0 = (bx & 31) * 128; Nz = kB * kS; }
  const float* __restrict__ X = p.Xf[z];
  const f16*   __restrict__ Y = p.Yh[z];
  f16* __restrict__ C = p.C[z];
  // which LDS buffer each operand feeds, and its global row base
  const int xr0 = (z == 2) ? n0 : m0;   // fp32 operand rows
  const int yr0 = (z == 2) ? m0 : n0;   // f16 operand rows

  __shared__ __align__(16) f16 As[2][128 * 32];
  __shared__ __align__(16) f16 Bs[2][128 * 32];
  f16* Xsb[2] = {(z == 2) ? Bs[0] : As[0], (z == 2) ? Bs[1] : As[1]};
  f16* Ysb[2] = {(z == 2) ? As[0] : Bs[0], (z == 2) ? As[1] : Bs[1]};

  const int t = threadIdx.x;
  const int lane = t & 63;
  const int wave = t >> 6;
  const int wm = (wave >> 1) * 64;
  const int wn = (wave & 1) * 64;
  const int col = lane & 15;
  const int quad = lane >> 4;

  f32x4 acc[4][4];
#pragma unroll
  for (int i = 0; i < 4; ++i)
#pragma unroll
    for (int j = 0; j < 4; ++j) acc[i][j] = (f32x4){0.f, 0.f, 0.f, 0.f};

  const int c0 = t, c1 = t + 256;
  const float* xg0 = X + (size_t)(xr0 + (c0 >> 2)) * K + (c0 & 3) * 8;
  const float* xg1 = X + (size_t)(xr0 + (c1 >> 2)) * K + (c1 & 3) * 8;
  const f16*   yg0 = Y + (size_t)(yr0 + (c0 >> 2)) * K + (c0 & 3) * 8;
  const f16*   yg1 = Y + (size_t)(yr0 + (c1 >> 2)) * K + (c1 & 3) * 8;

  // prologue: tile 0 -> buf 0
  {
    float4 xa0 = *(const float4*)(xg0), xb0 = *(const float4*)(xg0 + 4);
    float4 xa1 = *(const float4*)(xg1), xb1 = *(const float4*)(xg1 + 4);
    f16x8 y0 = *(const f16x8*)(yg0);
    f16x8 y1 = *(const f16x8*)(yg1);
    *(f16x8*)(Xsb[0] + c0 * 8) = cvt8(xa0, xb0);
    *(f16x8*)(Xsb[0] + c1 * 8) = cvt8(xa1, xb1);
    *(f16x8*)(Ysb[0] + c0 * 8) = y0;
    *(f16x8*)(Ysb[0] + c1 * 8) = y1;
  }

  for (int i = 0; i < NI; ++i) {
    const int cur = i & 1;
    float4 nxa0, nxb0, nxa1, nxb1;
    f16x8 ny0, ny1;
    if (i + 1 < NI) {
      const int ko = (i + 1) * 32;
      nxa0 = *(const float4*)(xg0 + ko); nxb0 = *(const float4*)(xg0 + ko + 4);
      nxa1 = *(const float4*)(xg1 + ko); nxb1 = *(const float4*)(xg1 + ko + 4);
      ny0 = *(const f16x8*)(yg0 + ko);
      ny1 = *(const f16x8*)(yg1 + ko);
    }
    __syncthreads();

    f16x8 af[4], bf[4];
#pragma unroll
    for (int mt = 0; mt < 4; ++mt)
      af[mt] = *(const f16x8*)(As[cur] + (wm + mt * 16 + col) * 32 + quad * 8);
#pragma unroll
    for (int nt = 0; nt < 4; ++nt)
      bf[nt] = *(const f16x8*)(Bs[cur] + (wn + nt * 16 + col) * 32 + quad * 8);
#pragma unroll
    for (int mt = 0; mt < 4; ++mt)
#pragma unroll
      for (int nt = 0; nt < 4; ++nt)
        acc[mt][nt] = __builtin_amdgcn_mfma_f32_16x16x32_f16(
            af[mt], bf[nt], acc[mt][nt], 0, 0, 0);

    if (i + 1 < NI) {
      const int nxt = 1 - cur;
      *(f16x8*)(Xsb[nxt] + c0 * 8) = cvt8(nxa0, nxb0);
      *(f16x8*)(Xsb[nxt] + c1 * 8) = cvt8(nxa1, nxb1);
      *(f16x8*)(Ysb[nxt] + c0 * 8) = ny0;
      *(f16x8*)(Ysb[nxt] + c1 * 8) = ny1;
    }
  }

  const int crow = m0 + wm + quad * 4;
  const int ccol = n0 + wn + col;
#pragma unroll
  for (int mt = 0; mt < 4; ++mt)
#pragma unroll
    for (int nt = 0; nt < 4; ++nt)
#pragma unroll
      for (int r = 0; r < 4; ++r)
        C[(size_t)(crow + mt * 16 + r) * Nz + ccol + nt * 16] =
            (f16)acc[mt][nt][r];
}

// --------- output projection: 64x128 tile, reg-prefetch pipeline ----------
__global__ __launch_bounds__(256) void gemm_out64(
    const f16* __restrict__ A, const f16* __restrict__ Bt,
    const float* __restrict__ bias, float* __restrict__ C, int M, int N, int K)
{
  __shared__ __align__(16) f16 As[2][64 * 32];
  __shared__ __align__(16) f16 Bs[2][128 * 32];
  const int t = threadIdx.x;
  const int lane = t & 63;
  const int wave = t >> 6;
  const int n0 = blockIdx.x * 128;
  const int m0 = blockIdx.y * 64;
  const int wm = (wave >> 1) * 32;
  const int wn = (wave & 1) * 64;
  const int col = lane & 15;
  const int quad = lane >> 4;
  const int NI = K / 32;

  f32x4 acc[2][4];
#pragma unroll
  for (int i = 0; i < 2; ++i)
#pragma unroll
    for (int j = 0; j < 4; ++j) acc[i][j] = (f32x4){0.f, 0.f, 0.f, 0.f};

  const int c0 = t, c1 = t + 256;
  const f16* a0 = A + (size_t)(m0 + (c0 >> 2)) * K + (c0 & 3) * 8;
  const f16* b0 = Bt + (size_t)(n0 + (c0 >> 2)) * K + (c0 & 3) * 8;
  const f16* b1 = Bt + (size_t)(n0 + (c1 >> 2)) * K + (c1 & 3) * 8;

  {
    f16x8 ra0 = *(const f16x8*)(a0);
    f16x8 rb0 = *(const f16x8*)(b0);
    f16x8 rb1 = *(const f16x8*)(b1);
    *(f16x8*)(As[0] + c0 * 8) = ra0;
    *(f16x8*)(Bs[0] + c0 * 8) = rb0;
    *(f16x8*)(Bs[0] + c1 * 8) = rb1;
  }

  for (int i = 0; i < NI; ++i) {
    const int cur = i & 1;
    f16x8 na0, nb0, nb1;
    if (i + 1 < NI) {
      const int ko = (i + 1) * 32;
      na0 = *(const f16x8*)(a0 + ko);
      nb0 = *(const f16x8*)(b0 + ko);
      nb1 = *(const f16x8*)(b1 + ko);
    }
    __syncthreads();

    f16x8 af[2], bf[4];
#pragma unroll
    for (int mt = 0; mt < 2; ++mt)
      af[mt] = *(const f16x8*)(As[cur] + (wm + mt * 16 + col) * 32 + quad * 8);
#pragma unroll
    for (int nt = 0; nt < 4; ++nt)
      bf[nt] = *(const f16x8*)(Bs[cur] + (wn + nt * 16 + col) * 32 + quad * 8);
#pragma unroll
    for (int mt = 0; mt < 2; ++mt)
#pragma unroll
      for (int nt = 0; nt < 4; ++nt)
        acc[mt][nt] = __builtin_amdgcn_mfma_f32_16x16x32_f16(
            af[mt], bf[nt], acc[mt][nt], 0, 0, 0);

    if (i + 1 < NI) {
      const int nxt = 1 - cur;
      *(f16x8*)(As[nxt] + c0 * 8) = na0;
      *(f16x8*)(Bs[nxt] + c0 * 8) = nb0;
      *(f16x8*)(Bs[nxt] + c1 * 8) = nb1;
    }
  }

  const int crow = m0 + wm + quad * 4;
  const int ccol = n0 + wn + col;
#pragma unroll
  for (int mt = 0; mt < 2; ++mt)
#pragma unroll
    for (int nt = 0; nt < 4; ++nt) {
      const float bv = bias[ccol + nt * 16];
#pragma unroll
      for (int r = 0; r < 4; ++r)
        C[(size_t)(crow + mt * 16 + r) * N + ccol + nt * 16] =
            acc[mt][nt][r] + bv;
    }
}

// ---------------- MFMA flash attention v3 (proven) + XCD-affinity grid -----
// 64 Q-rows/block (16/wave), grid 512 = 2 blocks/CU. blockIdx.x = (b,h) so
// all q-tiles of a head share linear%8 -> K/V stay in one XCD's L2.
__global__ __launch_bounds__(256) void flash_attn_mfma3(
    const f16* __restrict__ q, const f16* __restrict__ k,
    const f16* __restrict__ vT, f16* __restrict__ x)
{
  constexpr int LP = 72;
  constexpr int NT = kS / 64;
  __shared__ __align__(16) f16 Kt[2][64 * LP];
  __shared__ __align__(16) f16 Vt[2][64 * LP];
  __shared__ __align__(16) f16 Pb[4][16 * LP];

  const int t    = threadIdx.x;
  const int lane = t & 63;
  const int wave = t >> 6;
  const int col  = lane & 15;
  const int quad = lane >> 4;
  const int bh   = blockIdx.x;
  const int l0   = blockIdx.y * 64;
  const int h    = bh & (kHeads - 1);
  const int b    = bh >> 4;

  f16* Pw = Pb[wave];

  f16x8 qf[2];
  {
    const f16* src = q + ((size_t)b * kL + l0 + wave * 16 + col) * kDim + h * kHd;
    qf[0] = *(const f16x8*)(src + quad * 8);
    qf[1] = *(const f16x8*)(src + 32 + quad * 8);
#pragma unroll
    for (int u = 0; u < 8; ++u) {
      qf[0][u] = qf[0][u] * (f16)0.125f;
      qf[1][u] = qf[1][u] * (f16)0.125f;
    }
  }

  const int sr = t >> 2;
  const int sc = (t & 3) * 16;
  const f16* kbase = k + ((size_t)b * kS + sr) * kDim + h * kHd + sc;
  const f16* vbase = vT + ((size_t)(h * kHd + sr)) * (kB * kS) + b * kS + sc;

  float l_part[4];
  f32x4 accO[4];
#pragma unroll
  for (int r = 0; r < 4; ++r) l_part[r] = 0.f;
#pragma unroll
  for (int dt = 0; dt < 4; ++dt) accO[dt] = (f32x4){0.f, 0.f, 0.f, 0.f};

  {
    f16x8 k0v = *(const f16x8*)(kbase);
    f16x8 k1v = *(const f16x8*)(kbase + 8);
    f16x8 v0v = *(const f16x8*)(vbase);
    f16x8 v1v = *(const f16x8*)(vbase + 8);
    *(f16x8*)(Kt[0] + sr * LP + sc)     = k0v;
    *(f16x8*)(Kt[0] + sr * LP + sc + 8) = k1v;
    *(f16x8*)(Vt[0] + sr * LP + sc)     = v0v;
    *(f16x8*)(Vt[0] + sr * LP + sc + 8) = v1v;
  }

  for (int i = 0; i < NT; ++i) {
    const int cur = i & 1;
    f16x8 nk0, nk1, nv0, nv1;
    if (i + 1 < NT) {
      const f16* kn = kbase + (size_t)(i + 1) * 64 * kDim;
      const f16* vn = vbase + (i + 1) * 64;
      nk0 = *(const f16x8*)(kn);
      nk1 = *(const f16x8*)(kn + 8);
      nv0 = *(const f16x8*)(vn);
      nv1 = *(const f16x8*)(vn + 8);
    }
    __syncthreads();

    f32x4 s4[4];
#pragma unroll
    for (int ns = 0; ns < 4; ++ns) s4[ns] = (f32x4){0.f, 0.f, 0.f, 0.f};
#pragma unroll
    for (int ns = 0; ns < 4; ++ns) {
      f16x8 kf0 = *(const f16x8*)(Kt[cur] + (ns * 16 + col) * LP + quad * 8);
      f16x8 kf1 = *(const f16x8*)(Kt[cur] + (ns * 16 + col) * LP + 32 + quad * 8);
      s4[ns] = __builtin_amdgcn_mfma_f32_16x16x32_f16(qf[0], kf0, s4[ns], 0, 0, 0);
      s4[ns] = __builtin_amdgcn_mfma_f32_16x16x32_f16(qf[1], kf1, s4[ns], 0, 0, 0);
    }

#pragma unroll
    for (int r = 0; r < 4; ++r) {
      float rs = 0.f;
#pragma unroll
      for (int ns = 0; ns < 4; ++ns) {
        float pv = __expf(s4[ns][r]);
        Pw[(quad * 4 + r) * LP + ns * 16 + col] = (f16)pv;
        rs += pv;
      }
      l_part[r] += rs;
    }

    f16x8 pf0 = *(const f16x8*)(Pw + col * LP + quad * 8);
    f16x8 pf1 = *(const f16x8*)(Pw + col * LP + 32 + quad * 8);
#pragma unroll
    for (int dt = 0; dt < 4; ++dt) {
      f16x8 vf0 = *(const f16x8*)(Vt[cur] + (dt * 16 + col) * LP + quad * 8);
      f16x8 vf1 = *(const f16x8*)(Vt[cur] + (dt * 16 + col) * LP + 32 + quad * 8);
      accO[dt] = __builtin_amdgcn_mfma_f32_16x16x32_f16(pf0, vf0, accO[dt], 0, 0, 0);
      accO[dt] = __builtin_amdgcn_mfma_f32_16x16x32_f16(pf1, vf1, accO[dt], 0, 0, 0);
    }

    if (i + 1 < NT) {
      const int nxt = 1 - cur;
      *(f16x8*)(Kt[nxt] + sr * LP + sc)     = nk0;
      *(f16x8*)(Kt[nxt] + sr * LP + sc + 8) = nk1;
      *(f16x8*)(Vt[nxt] + sr * LP + sc)     = nv0;
      *(f16x8*)(Vt[nxt] + sr * LP + sc + 8) = nv1;
    }
  }

#pragma unroll
  for (int r = 0; r < 4; ++r) {
    float lv = l_part[r];
    lv += __shfl_xor(lv, 1, 16);
    lv += __shfl_xor(lv, 2, 16);
    lv += __shfl_xor(lv, 4, 16);
    lv += __shfl_xor(lv, 8, 16);
    const float inv = 1.f / lv;
    const size_t row = (size_t)b * kL + l0 + wave * 16 + quad * 4 + r;
#pragma unroll
    for (int dt = 0; dt < 4; ++dt)
      x[row * kDim + h * kHd + dt * 16 + col] = (f16)(accO[dt][r] * inv);
  }
}

}  // namespace

extern "C" void kernel_launch(void* const* d_in, const int* in_sizes, int n_in,
                              void* d_out, int out_size, void* d_ws, size_t ws_size,
                              hipStream_t stream) {
  const float* query = (const float*)d_in[0];
  const float* key   = (const float*)d_in[1];
  const float* value = (const float*)d_in[2];
  const float* Wq    = (const float*)d_in[3];
  const float* Wk    = (const float*)d_in[4];
  const float* Wv    = (const float*)d_in[5];
  const float* Wo    = (const float*)d_in[6];
  const float* bo    = (const float*)d_in[7];
  float* out = (float*)d_out;

  f16* ws = (f16*)d_ws;
  f16* wqt = ws;
  f16* wkt = wqt + (size_t)kDim * kDim;
  f16* wvt = wkt + (size_t)kDim * kDim;
  f16* wot = wvt + (size_t)kDim * kDim;
  f16* qp  = wot + (size_t)kDim * kDim;
  f16* kp  = qp + (size_t)kB * kL * kDim;
  f16* vpT = kp + (size_t)kB * kS * kDim;   // [kDim][kB*kS] = V^T
  f16* xh  = vpT + (size_t)kB * kS * kDim;

  PrepWArgs pw;
  pw.w[0] = Wq; pw.wt[0] = wqt;
  pw.w[1] = Wk; pw.wt[1] = wkt;
  pw.w[2] = Wv; pw.wt[2] = wvt;
  pw.w[3] = Wo; pw.wt[3] = wot;
  prep_w<<<dim3(1024, 4), 256, 0, stream>>>(pw);

  ProjArgs pa;
  pa.Xf[0] = query; pa.Yh[0] = wqt; pa.C[0] = qp;
  pa.Xf[1] = key;   pa.Yh[1] = wkt; pa.C[1] = kp;
  pa.Xf[2] = value; pa.Yh[2] = wvt; pa.C[2] = vpT;
  gemm_proj<<<dim3(640), 256, 0, stream>>>(pa);

  flash_attn_mfma3<<<dim3(kB * kHeads, kL / 64), 256, 0, stream>>>(
      qp, kp, vpT, xh);

  gemm_out64<<<dim3(kDim / 128, (kB * kL) / 64), 256, 0, stream>>>(
      xh, wot, bo, out, kB * kL, kDim, kDim);
}

// Round 10
// 198.872 us; speedup vs baseline: 1.0544x; 1.0544x over previous
//
#include <hip/hip_runtime.h>

namespace {

typedef _Float16 f16;
typedef __attribute__((ext_vector_type(4))) _Float16 f16x4;
typedef __attribute__((ext_vector_type(8))) _Float16 f16x8;
typedef __attribute__((ext_vector_type(4))) float f32x4;

constexpr int kDim   = 1024;
constexpr int kHeads = 16;
constexpr int kHd    = 64;
constexpr int kB     = 2;
constexpr int kL     = 1024;
constexpr int kS     = 2048;

// ---------------- prep: casts (y<3) + weight transposes (y>=3) ------------
struct PrepArgs {
  const float* csrc[3];
  f16* cdst[3];
  int cn[3];
  const float* w[4];
  f16* wt[4];
};

__global__ __launch_bounds__(256) void prep(PrepArgs a) {
  __shared__ float T[32][33];
  const int y = blockIdx.y;
  if (y < 3) {
    const int i = (blockIdx.x * 256 + threadIdx.x) * 8;
    if (i >= a.cn[y]) return;
    const float* __restrict__ src = a.csrc[y];
    float4 v0 = *(const float4*)(src + i);
    float4 v1 = *(const float4*)(src + i + 4);
    f16x8 h = {(f16)v0.x, (f16)v0.y, (f16)v0.z, (f16)v0.w,
               (f16)v1.x, (f16)v1.y, (f16)v1.z, (f16)v1.w};
    *(f16x8*)(a.cdst[y] + i) = h;
  } else {
    if (blockIdx.x >= 1024) return;
    const int z = y - 3;
    const float* __restrict__ W = a.w[z];
    f16* __restrict__ Wt = a.wt[z];
    const int n0 = (blockIdx.x & 31) * 32;
    const int k0 = (blockIdx.x >> 5) * 32;
    const int r = threadIdx.x >> 3;
    const int c = (threadIdx.x & 7) * 4;
    float4 v = *(const float4*)(W + (size_t)(k0 + r) * kDim + n0 + c);
    T[c + 0][r] = v.x; T[c + 1][r] = v.y; T[c + 2][r] = v.z; T[c + 3][r] = v.w;
    __syncthreads();
    f16x4 h = {(f16)T[r][c], (f16)T[r][c + 1], (f16)T[r][c + 2], (f16)T[r][c + 3]};
    *(f16x4*)(Wt + (size_t)(n0 + r) * kDim + k0 + c) = h;
  }
}

// ------------- fused projection GEMMs, f16 operands, reg-prefetch ---------
// Flat 640-block grid: [0,128) Q, [128,384) K, [384,640) V^T.
struct ProjArgs {
  const f16* A[3];
  const f16* Bt[3];
  f16* C[3];
};

__global__ __launch_bounds__(256) void gemm_proj(ProjArgs p) {
  constexpr int K = kDim;
  constexpr int NI = K / 32;
  int bx = blockIdx.x;
  int z, m0, n0, Nz;
  if (bx < 128)      { z = 0; m0 = (bx >> 3) * 128; n0 = (bx & 7) * 128; Nz = kDim; }
  else if (bx < 384) { bx -= 128; z = 1; m0 = (bx >> 3) * 128; n0 = (bx & 7) * 128; Nz = kDim; }
  else               { bx -= 384; z = 2; m0 = (bx >> 5) * 128; n0 = (bx & 31) * 128; Nz = kB * kS; }
  const f16* __restrict__ A  = p.A[z];
  const f16* __restrict__ Bt = p.Bt[z];
  f16* __restrict__ C = p.C[z];

  __shared__ __align__(16) f16 As[2][128 * 32];
  __shared__ __align__(16) f16 Bs[2][128 * 32];
  const int t = threadIdx.x;
  const int lane = t & 63;
  const int wave = t >> 6;
  const int wm = (wave >> 1) * 64;
  const int wn = (wave & 1) * 64;
  const int col = lane & 15;
  const int quad = lane >> 4;

  f32x4 acc[4][4];
#pragma unroll
  for (int i = 0; i < 4; ++i)
#pragma unroll
    for (int j = 0; j < 4; ++j) acc[i][j] = (f32x4){0.f, 0.f, 0.f, 0.f};

  const int c0 = t, c1 = t + 256;
  const f16* a0 = A + (size_t)(m0 + (c0 >> 2)) * K + (c0 & 3) * 8;
  const f16* a1 = A + (size_t)(m0 + (c1 >> 2)) * K + (c1 & 3) * 8;
  const f16* b0 = Bt + (size_t)(n0 + (c0 >> 2)) * K + (c0 & 3) * 8;
  const f16* b1 = Bt + (size_t)(n0 + (c1 >> 2)) * K + (c1 & 3) * 8;

  {
    f16x8 ra0 = *(const f16x8*)(a0);
    f16x8 ra1 = *(const f16x8*)(a1);
    f16x8 rb0 = *(const f16x8*)(b0);
    f16x8 rb1 = *(const f16x8*)(b1);
    *(f16x8*)(As[0] + c0 * 8) = ra0;
    *(f16x8*)(As[0] + c1 * 8) = ra1;
    *(f16x8*)(Bs[0] + c0 * 8) = rb0;
    *(f16x8*)(Bs[0] + c1 * 8) = rb1;
  }

  for (int i = 0; i < NI; ++i) {
    const int cur = i & 1;
    f16x8 na0, na1, nb0, nb1;
    if (i + 1 < NI) {
      const int ko = (i + 1) * 32;
      na0 = *(const f16x8*)(a0 + ko);
      na1 = *(const f16x8*)(a1 + ko);
      nb0 = *(const f16x8*)(b0 + ko);
      nb1 = *(const f16x8*)(b1 + ko);
    }
    __syncthreads();

    f16x8 af[4], bf[4];
#pragma unroll
    for (int mt = 0; mt < 4; ++mt)
      af[mt] = *(const f16x8*)(As[cur] + (wm + mt * 16 + col) * 32 + quad * 8);
#pragma unroll
    for (int nt = 0; nt < 4; ++nt)
      bf[nt] = *(const f16x8*)(Bs[cur] + (wn + nt * 16 + col) * 32 + quad * 8);
#pragma unroll
    for (int mt = 0; mt < 4; ++mt)
#pragma unroll
      for (int nt = 0; nt < 4; ++nt)
        acc[mt][nt] = __builtin_amdgcn_mfma_f32_16x16x32_f16(
            af[mt], bf[nt], acc[mt][nt], 0, 0, 0);

    if (i + 1 < NI) {
      const int nxt = 1 - cur;
      *(f16x8*)(As[nxt] + c0 * 8) = na0;
      *(f16x8*)(As[nxt] + c1 * 8) = na1;
      *(f16x8*)(Bs[nxt] + c0 * 8) = nb0;
      *(f16x8*)(Bs[nxt] + c1 * 8) = nb1;
    }
  }

  const int crow = m0 + wm + quad * 4;
  const int ccol = n0 + wn + col;
#pragma unroll
  for (int mt = 0; mt < 4; ++mt)
#pragma unroll
    for (int nt = 0; nt < 4; ++nt)
#pragma unroll
      for (int r = 0; r < 4; ++r)
        C[(size_t)(crow + mt * 16 + r) * Nz + ccol + nt * 16] =
            (f16)acc[mt][nt][r];
}

// --------- output projection: 64x64 tiles, grid 512 = 2 blocks/CU ---------
__global__ __launch_bounds__(256) void gemm_out(
    const f16* __restrict__ A, const f16* __restrict__ Bt,
    const float* __restrict__ bias, float* __restrict__ C, int M, int N, int K)
{
  __shared__ __align__(16) f16 As[2][64 * 32];
  __shared__ __align__(16) f16 Bs[2][64 * 32];
  const int t = threadIdx.x;
  const int lane = t & 63;
  const int wave = t >> 6;
  const int n0 = blockIdx.x * 64;
  const int m0 = blockIdx.y * 64;
  const int wm = (wave >> 1) * 32;
  const int wn = (wave & 1) * 32;
  const int col = lane & 15;
  const int quad = lane >> 4;
  const int NI = K / 32;

  f32x4 acc[2][2];
#pragma unroll
  for (int i = 0; i < 2; ++i)
#pragma unroll
    for (int j = 0; j < 2; ++j) acc[i][j] = (f32x4){0.f, 0.f, 0.f, 0.f};

  const f16* a0 = A + (size_t)(m0 + (t >> 2)) * K + (t & 3) * 8;
  const f16* b0 = Bt + (size_t)(n0 + (t >> 2)) * K + (t & 3) * 8;

  {
    f16x8 ra0 = *(const f16x8*)(a0);
    f16x8 rb0 = *(const f16x8*)(b0);
    *(f16x8*)(As[0] + t * 8) = ra0;
    *(f16x8*)(Bs[0] + t * 8) = rb0;
  }

  for (int i = 0; i < NI; ++i) {
    const int cur = i & 1;
    f16x8 na0, nb0;
    if (i + 1 < NI) {
      const int ko = (i + 1) * 32;
      na0 = *(const f16x8*)(a0 + ko);
      nb0 = *(const f16x8*)(b0 + ko);
    }
    __syncthreads();

    f16x8 af[2], bf[2];
#pragma unroll
    for (int mt = 0; mt < 2; ++mt)
      af[mt] = *(const f16x8*)(As[cur] + (wm + mt * 16 + col) * 32 + quad * 8);
#pragma unroll
    for (int nt = 0; nt < 2; ++nt)
      bf[nt] = *(const f16x8*)(Bs[cur] + (wn + nt * 16 + col) * 32 + quad * 8);
#pragma unroll
    for (int mt = 0; mt < 2; ++mt)
#pragma unroll
      for (int nt = 0; nt < 2; ++nt)
        acc[mt][nt] = __builtin_amdgcn_mfma_f32_16x16x32_f16(
            af[mt], bf[nt], acc[mt][nt], 0, 0, 0);

    if (i + 1 < NI) {
      const int nxt = 1 - cur;
      *(f16x8*)(As[nxt] + t * 8) = na0;
      *(f16x8*)(Bs[nxt] + t * 8) = nb0;
    }
  }

  const int crow = m0 + wm + quad * 4;
  const int ccol = n0 + wn + col;
#pragma unroll
  for (int mt = 0; mt < 2; ++mt)
#pragma unroll
    for (int nt = 0; nt < 2; ++nt) {
      const float bv = bias[ccol + nt * 16];
#pragma unroll
      for (int r = 0; r < 4; ++r)
        C[(size_t)(crow + mt * 16 + r) * N + ccol + nt * 16] =
            acc[mt][nt][r] + bv;
    }
}

// ---------------- MFMA flash attention v3 + XCD-affinity grid -------------
// 64 Q-rows/block (16/wave), grid (32 bh, 16 qtile) = 512 = 2 blocks/CU.
__global__ __launch_bounds__(256) void flash_attn_mfma3(
    const f16* __restrict__ q, const f16* __restrict__ k,
    const f16* __restrict__ vT, f16* __restrict__ x)
{
  constexpr int LP = 72;
  constexpr int NT = kS / 64;
  __shared__ __align__(16) f16 Kt[2][64 * LP];
  __shared__ __align__(16) f16 Vt[2][64 * LP];
  __shared__ __align__(16) f16 Pb[4][16 * LP];

  const int t    = threadIdx.x;
  const int lane = t & 63;
  const int wave = t >> 6;
  const int col  = lane & 15;
  const int quad = lane >> 4;
  const int bh   = blockIdx.x;
  const int l0   = blockIdx.y * 64;
  const int h    = bh & (kHeads - 1);
  const int b    = bh >> 4;

  f16* Pw = Pb[wave];

  f16x8 qf[2];
  {
    const f16* src = q + ((size_t)b * kL + l0 + wave * 16 + col) * kDim + h * kHd;
    qf[0] = *(const f16x8*)(src + quad * 8);
    qf[1] = *(const f16x8*)(src + 32 + quad * 8);
#pragma unroll
    for (int u = 0; u < 8; ++u) {
      qf[0][u] = qf[0][u] * (f16)0.125f;
      qf[1][u] = qf[1][u] * (f16)0.125f;
    }
  }

  const int sr = t >> 2;
  const int sc = (t & 3) * 16;
  const f16* kbase = k + ((size_t)b * kS + sr) * kDim + h * kHd + sc;
  const f16* vbase = vT + ((size_t)(h * kHd + sr)) * (kB * kS) + b * kS + sc;

  float l_part[4];
  f32x4 accO[4];
#pragma unroll
  for (int r = 0; r < 4; ++r) l_part[r] = 0.f;
#pragma unroll
  for (int dt = 0; dt < 4; ++dt) accO[dt] = (f32x4){0.f, 0.f, 0.f, 0.f};

  {
    f16x8 k0v = *(const f16x8*)(kbase);
    f16x8 k1v = *(const f16x8*)(kbase + 8);
    f16x8 v0v = *(const f16x8*)(vbase);
    f16x8 v1v = *(const f16x8*)(vbase + 8);
    *(f16x8*)(Kt[0] + sr * LP + sc)     = k0v;
    *(f16x8*)(Kt[0] + sr * LP + sc + 8) = k1v;
    *(f16x8*)(Vt[0] + sr * LP + sc)     = v0v;
    *(f16x8*)(Vt[0] + sr * LP + sc + 8) = v1v;
  }

  for (int i = 0; i < NT; ++i) {
    const int cur = i & 1;
    f16x8 nk0, nk1, nv0, nv1;
    if (i + 1 < NT) {
      const f16* kn = kbase + (size_t)(i + 1) * 64 * kDim;
      const f16* vn = vbase + (i + 1) * 64;
      nk0 = *(const f16x8*)(kn);
      nk1 = *(const f16x8*)(kn + 8);
      nv0 = *(const f16x8*)(vn);
      nv1 = *(const f16x8*)(vn + 8);
    }
    __syncthreads();

    f32x4 s4[4];
#pragma unroll
    for (int ns = 0; ns < 4; ++ns) s4[ns] = (f32x4){0.f, 0.f, 0.f, 0.f};
#pragma unroll
    for (int ns = 0; ns < 4; ++ns) {
      f16x8 kf0 = *(const f16x8*)(Kt[cur] + (ns * 16 + col) * LP + quad * 8);
      f16x8 kf1 = *(const f16x8*)(Kt[cur] + (ns * 16 + col) * LP + 32 + quad * 8);
      s4[ns] = __builtin_amdgcn_mfma_f32_16x16x32_f16(qf[0], kf0, s4[ns], 0, 0, 0);
      s4[ns] = __builtin_amdgcn_mfma_f32_16x16x32_f16(qf[1], kf1, s4[ns], 0, 0, 0);
    }

#pragma unroll
    for (int r = 0; r < 4; ++r) {
      float rs = 0.f;
#pragma unroll
      for (int ns = 0; ns < 4; ++ns) {
        float pv = __expf(s4[ns][r]);
        Pw[(quad * 4 + r) * LP + ns * 16 + col] = (f16)pv;
        rs += pv;
      }
      l_part[r] += rs;
    }

    f16x8 pf0 = *(const f16x8*)(Pw + col * LP + quad * 8);
    f16x8 pf1 = *(const f16x8*)(Pw + col * LP + 32 + quad * 8);
#pragma unroll
    for (int dt = 0; dt < 4; ++dt) {
      f16x8 vf0 = *(const f16x8*)(Vt[cur] + (dt * 16 + col) * LP + quad * 8);
      f16x8 vf1 = *(const f16x8*)(Vt[cur] + (dt * 16 + col) * LP + 32 + quad * 8);
      accO[dt] = __builtin_amdgcn_mfma_f32_16x16x32_f16(pf0, vf0, accO[dt], 0, 0, 0);
      accO[dt] = __builtin_amdgcn_mfma_f32_16x16x32_f16(pf1, vf1, accO[dt], 0, 0, 0);
    }

    if (i + 1 < NT) {
      const int nxt = 1 - cur;
      *(f16x8*)(Kt[nxt] + sr * LP + sc)     = nk0;
      *(f16x8*)(Kt[nxt] + sr * LP + sc + 8) = nk1;
      *(f16x8*)(Vt[nxt] + sr * LP + sc)     = nv0;
      *(f16x8*)(Vt[nxt] + sr * LP + sc + 8) = nv1;
    }
  }

#pragma unroll
  for (int r = 0; r < 4; ++r) {
    float lv = l_part[r];
    lv += __shfl_xor(lv, 1, 16);
    lv += __shfl_xor(lv, 2, 16);
    lv += __shfl_xor(lv, 4, 16);
    lv += __shfl_xor(lv, 8, 16);
    const float inv = 1.f / lv;
    const size_t row = (size_t)b * kL + l0 + wave * 16 + quad * 4 + r;
#pragma unroll
    for (int dt = 0; dt < 4; ++dt)
      x[row * kDim + h * kHd + dt * 16 + col] = (f16)(accO[dt][r] * inv);
  }
}

}  // namespace

extern "C" void kernel_launch(void* const* d_in, const int* in_sizes, int n_in,
                              void* d_out, int out_size, void* d_ws, size_t ws_size,
                              hipStream_t stream) {
  const float* query = (const float*)d_in[0];
  const float* key   = (const float*)d_in[1];
  const float* value = (const float*)d_in[2];
  const float* Wq    = (const float*)d_in[3];
  const float* Wk    = (const float*)d_in[4];
  const float* Wv    = (const float*)d_in[5];
  const float* Wo    = (const float*)d_in[6];
  const float* bo    = (const float*)d_in[7];
  float* out = (float*)d_out;

  f16* ws = (f16*)d_ws;
  f16* qh  = ws;
  f16* kh  = qh + (size_t)kB * kL * kDim;
  f16* vh  = kh + (size_t)kB * kS * kDim;
  f16* wqt = vh + (size_t)kB * kS * kDim;
  f16* wkt = wqt + (size_t)kDim * kDim;
  f16* wvt = wkt + (size_t)kDim * kDim;
  f16* wot = wvt + (size_t)kDim * kDim;
  f16* qp  = wot + (size_t)kDim * kDim;
  f16* kp  = qp + (size_t)kB * kL * kDim;
  f16* vpT = kp + (size_t)kB * kS * kDim;   // [kDim][kB*kS] = V^T
  f16* xh  = vpT + (size_t)kB * kS * kDim;

  PrepArgs pr;
  pr.csrc[0] = query; pr.cdst[0] = qh; pr.cn[0] = kB * kL * kDim;
  pr.csrc[1] = key;   pr.cdst[1] = kh; pr.cn[1] = kB * kS * kDim;
  pr.csrc[2] = value; pr.cdst[2] = vh; pr.cn[2] = kB * kS * kDim;
  pr.w[0] = Wq; pr.wt[0] = wqt;
  pr.w[1] = Wk; pr.wt[1] = wkt;
  pr.w[2] = Wv; pr.wt[2] = wvt;
  pr.w[3] = Wo; pr.wt[3] = wot;
  prep<<<dim3(2048, 7), 256, 0, stream>>>(pr);

  ProjArgs pa;
  pa.A[0] = qh;  pa.Bt[0] = wqt; pa.C[0] = qp;
  pa.A[1] = kh;  pa.Bt[1] = wkt; pa.C[1] = kp;
  pa.A[2] = wvt; pa.Bt[2] = vh;  pa.C[2] = vpT;
  gemm_proj<<<dim3(640), 256, 0, stream>>>(pa);

  flash_attn_mfma3<<<dim3(kB * kHeads, kL / 64), 256, 0, stream>>>(
      qp, kp, vpT, xh);

  gemm_out<<<dim3(kDim / 64, (kB * kL) / 64), 256, 0, stream>>>(
      xh, wot, bo, out, kB * kL, kDim, kDim);
}